// Round 14
// baseline (2543.360 us; speedup 1.0000x reference)
//
#include <hip/hip_runtime.h>

typedef _Float16 half8 __attribute__((ext_vector_type(8)));
typedef _Float16 f16x2 __attribute__((ext_vector_type(2)));
typedef float floatx4 __attribute__((ext_vector_type(4)));

#define NB 256    // batch
#define NT 512    // time
#define NI 64     // input
#define NH 256    // hidden
#define NSEQ 16   // sequences per block
#define NBLK (NB / NSEQ)   // 16 blocks
#define THR 1024           // 16 waves
#define HS 344             // H row stride in f16

// B-fragment pack (VALIDATED R9-R13): 480 frags x 64 lanes x 8 f16.
// Cols: [0,256)=r, [256,512)=z, [512,768)=h_n, [768,1024)=i_n. K: [0,256)=h, [256,320)=x.
// frag f: r: tt*10+kb; z: 160+tt*10+kb; h_n: 320+tt*8+kb (kb<8); i_n: 448+tt*2+(kb-8).
// wb[f*512 + lane*8 + i] = W[k = kb*32 + (lane>>4)*8 + i][n = tt*16 + (lane&15)]
#define WB_N (480 * 512)

__global__ __launch_bounds__(256) void gru_prep_kernel(
    const float* __restrict__ w_ih, const float* __restrict__ w_hh,
    _Float16* __restrict__ wb)
{
  int n = blockIdx.x * 256 + threadIdx.x;
  if (n >= WB_N) return;
  int i = n & 7, l = (n >> 3) & 63, f = n >> 9;
  int q = l >> 4, col = l & 15;
  int tt, kb, gate;
  if (f < 160)      { tt = f / 10;               kb = f % 10;        gate = 0; }
  else if (f < 320) { int f2 = f - 160; tt = f2 / 10; kb = f2 % 10;  gate = 1; }
  else if (f < 448) { int f3 = f - 320; tt = f3 / 8;  kb = f3 % 8;   gate = 2; }
  else              { int f4 = f - 448; tt = f4 / 2;  kb = 8 + (f4 & 1); gate = 3; }
  int j = (tt & 15) * 16 + col;
  int k = kb * 32 + q * 8 + i;
  float v;
  if (gate == 0)      v = (k < 256) ? w_hh[(0   + j) * 256 + k] : w_ih[(0   + j) * 64 + (k - 256)];
  else if (gate == 1) v = (k < 256) ? w_hh[(256 + j) * 256 + k] : w_ih[(256 + j) * 64 + (k - 256)];
  else if (gate == 2) v = w_hh[(512 + j) * 256 + k];
  else                v = w_ih[(512 + j) * 64 + (k - 256)];
  wb[n] = (_Float16)v;
}

__device__ __forceinline__ float sigm(float v) {
  return __builtin_amdgcn_rcpf(1.0f + __expf(-v));
}
__device__ __forceinline__ float tanh_f(float v) {
  return 1.0f - 2.0f * __builtin_amdgcn_rcpf(1.0f + __expf(2.0f * v));
}

#define MFMA16(a, b, c) __builtin_amdgcn_mfma_f32_16x16x32_f16(a, b, c, 0, 0, 0)
#define FDOT(W, X, A) __builtin_amdgcn_fdot2(__builtin_bit_cast(f16x2, W), \
                                             __builtin_bit_cast(f16x2, X), A, false)

// ---------------- batched MFMA recurrence: 1 block = 16 sequences (R13 skeleton) ----------------
// KEY CHANGE vs R13: amdgpu_waves_per_eu(4,4) pins the occupancy target to the
// true value (1 block/CU = 4 waves/SIMD -> 512 VGPR budget). R10-R13 compiled at
// VGPR=64 — the "persistent" fragments were silently re-loaded from L1/L2 every
// step (~320 KB/step/CU = the real bottleneck). Now ALL 30 weight fragments
// (r10+z10+n8+i2 = 120 VGPRs) are held resident; WN leaves LDS entirely.
__global__
__attribute__((amdgpu_flat_work_group_size(THR, THR), amdgpu_waves_per_eu(4, 4)))
void gru_kernel(
    const float* __restrict__ x,      // [B, T, I]
    const float* __restrict__ b_ih,   // [768]
    const float* __restrict__ b_hh,   // [768]
    const _Float16* __restrict__ wb,  // packed B fragments
    _Float16* __restrict__ HD)        // [NT][NB][NH] f16 hidden-state dump
{
  __shared__ __align__(16) _Float16 H[2][NSEQ][HS];   // 22016 B, double-buffered

  const int tid  = threadIdx.x;
  const int lane = tid & 63;
  const int w    = tid >> 6;        // wave 0..15
  const int q    = lane >> 4;       // quad 0..3
  const int col  = lane & 15;
  const int b0   = blockIdx.x * NSEQ;
  const int j    = w * 16 + col;    // hidden unit owned in epilogue

  // ---- ALL weight fragments resident: 30 named half8 = 120 VGPRs ----
  const _Float16* wbL = wb + (size_t)lane * 8;
#define LBR(k) const half8 BR##k = *(const half8*)(wbL + (size_t)(w * 10 + (k)) * 512);
  LBR(0) LBR(1) LBR(2) LBR(3) LBR(4) LBR(5) LBR(6) LBR(7) LBR(8) LBR(9)
#undef LBR
#define LBZ(k) const half8 BZ##k = *(const half8*)(wbL + (size_t)(160 + w * 10 + (k)) * 512);
  LBZ(0) LBZ(1) LBZ(2) LBZ(3) LBZ(4) LBZ(5) LBZ(6) LBZ(7) LBZ(8) LBZ(9)
#undef LBZ
#define LBN(k) const half8 BN##k = *(const half8*)(wbL + (size_t)(320 + w * 8 + (k)) * 512);
  LBN(0) LBN(1) LBN(2) LBN(3) LBN(4) LBN(5) LBN(6) LBN(7)
#undef LBN
  const half8 BI0 = *(const half8*)(wbL + (size_t)(448 + w * 2 + 0) * 512);
  const half8 BI1 = *(const half8*)(wbL + (size_t)(448 + w * 2 + 1) * 512);

  const float br   = b_ih[j] + b_hh[j];
  const float bz   = b_ih[256 + j] + b_hh[256 + j];
  const float bin_ = b_ih[512 + j];
  const float bhn  = b_hh[512 + j];

  // ---- init: zero H (both buffers), then x(t=0) into H[0] ----
  {
    float4* hz = (float4*)H;
    #pragma unroll
    for (int it = 0; it < 2; ++it) {
      int idx = tid + it * THR;
      if (idx < (int)(sizeof(H) / 16)) hz[idx] = float4{0, 0, 0, 0};
    }
  }
  __syncthreads();
  H[0][tid >> 6][256 + (tid & 63)] =
      (_Float16)x[(size_t)(b0 + (tid >> 6)) * (NT * NI) + (tid & 63)];
  float h0 = 0.0f, h1 = 0.0f, h2 = 0.0f, h3 = 0.0f;
  const float* xp = x + (size_t)(b0 + (tid >> 6)) * (NT * NI) + 64 + (tid & 63);
  __syncthreads();

  for (int t = 0; t < NT; ++t) {
    const int cur = t & 1, nxt = cur ^ 1;
    float xv = 0.0f;
    if (t + 1 < NT) xv = xp[(size_t)t * 64];

    // ---- dump h_{t-1} (h-part of H[cur]) to HD[t-1]: 8 b128 reads + 8 stores ----
    if (t > 0 && tid < 512) {
      int row = tid >> 5, ch = tid & 31;
      float4 hv = *(const float4*)&H[cur][row][ch * 8];
      *(float4*)(HD + ((size_t)(t - 1) * NB + b0 + row) * NH + ch * 8) = hv;
    }

    // ---- GEMM: A row = seq = col (validated), 30 MFMAs/wave, all-register B ----
    const _Float16* hrow = &H[cur][col][q * 8];
    floatx4 cR = {0, 0, 0, 0}, cZ = {0, 0, 0, 0}, cN = {0, 0, 0, 0}, cI = {0, 0, 0, 0};
#define KBN(k) { \
    half8 a = *(const half8*)(hrow + (k) * 32); \
    cR = MFMA16(a, BR##k, cR); \
    cZ = MFMA16(a, BZ##k, cZ); \
    cN = MFMA16(a, BN##k, cN); }
    KBN(0) KBN(1) KBN(2) KBN(3) KBN(4) KBN(5) KBN(6) KBN(7)
#undef KBN
    { half8 a = *(const half8*)(hrow + 8 * 32);
      cR = MFMA16(a, BR8, cR); cZ = MFMA16(a, BZ8, cZ); cI = MFMA16(a, BI0, cI); }
    { half8 a = *(const half8*)(hrow + 9 * 32);
      cR = MFMA16(a, BR9, cR); cZ = MFMA16(a, BZ9, cZ); cI = MFMA16(a, BI1, cI); }

    // ---- in-register epilogue: lane owns (j, seqs q*4..q*4+3) ----
#define GATE(m, hvar) { \
    float rr = sigm(cR[m] + br); \
    float zz = sigm(cZ[m] + bz); \
    float nn = tanh_f(cI[m] + bin_ + rr * (cN[m] + bhn)); \
    hvar = (1.0f - zz) * nn + zz * hvar; \
    H[nxt][q * 4 + (m)][j] = (_Float16)hvar; }
    GATE(0, h0) GATE(1, h1) GATE(2, h2) GATE(3, h3)
#undef GATE
    if (t + 1 < NT) H[nxt][tid >> 6][256 + (tid & 63)] = (_Float16)xv;

    __syncthreads();   // the single per-step barrier
  }

  // ---- final dump: h_{NT-1} lives in H[0] (NT even) ----
  if (tid < 512) {
    int row = tid >> 5, ch = tid & 31;
    float4 hv = *(const float4*)&H[0][row][ch * 8];
    *(float4*)(HD + ((size_t)(NT - 1) * NB + b0 + row) * NH + ch * 8) = hv;
  }
}

// ---------------- epilogue: out[t][b] = HD[t][b][:] . w_out + b_out ----------------
__global__ __launch_bounds__(256) void gru_out_kernel(
    const _Float16* __restrict__ HD, const float* __restrict__ w_out,
    const float* __restrict__ b_out, float* __restrict__ out)
{
  __shared__ __align__(16) _Float16 WL[NH];
  int tid = threadIdx.x;
  WL[tid] = (_Float16)w_out[tid];
  __syncthreads();
  int gid = blockIdx.x * 256 + tid;          // gid = t*NB + b
  const float4* hp = (const float4*)(HD + (size_t)gid * NH);
  const float4* wp = (const float4*)WL;
  float acc = 0.0f;
  #pragma unroll
  for (int i = 0; i < NH / 8; ++i) {
    float4 hv = hp[i];
    float4 wv = wp[i];
    acc = FDOT(hv.x, wv.x, acc);
    acc = FDOT(hv.y, wv.y, acc);
    acc = FDOT(hv.z, wv.z, acc);
    acc = FDOT(hv.w, wv.w, acc);
  }
  out[gid] = acc + b_out[0];
}

extern "C" void kernel_launch(void* const* d_in, const int* in_sizes, int n_in,
                              void* d_out, int out_size, void* d_ws, size_t ws_size,
                              hipStream_t stream) {
  const float* x     = (const float*)d_in[0];
  const float* w_ih  = (const float*)d_in[1];
  const float* w_hh  = (const float*)d_in[2];
  const float* b_ih  = (const float*)d_in[3];
  const float* b_hh  = (const float*)d_in[4];
  const float* w_out = (const float*)d_in[5];
  const float* b_out = (const float*)d_in[6];
  float* out = (float*)d_out;

  _Float16* wb = (_Float16*)d_ws;            // 480 KB packed B fragments
  _Float16* HD = wb + WB_N;                  // 64 MB hidden-state dump (16B-aligned)

  gru_prep_kernel<<<(WB_N + 255) / 256, 256, 0, stream>>>(w_ih, w_hh, wb);
  gru_kernel<<<NBLK, THR, 0, stream>>>(x, b_ih, b_hh, wb, HD);
  gru_out_kernel<<<(NT * NB) / 256, 256, 0, stream>>>(HD, w_out, b_out, out);
}